// Round 4
// baseline (761.447 us; speedup 1.0000x reference)
//
#include <hip/hip_runtime.h>
#include <cstdint>
#include <cstddef>

// ---- types ----
typedef unsigned short u16;
typedef float  f32x4  __attribute__((ext_vector_type(4)));
typedef __bf16 bf16x8 __attribute__((ext_vector_type(8)));
typedef unsigned short us8 __attribute__((ext_vector_type(8)));
typedef unsigned short us4 __attribute__((ext_vector_type(4)));
typedef float  f32x4v __attribute__((ext_vector_type(4)));
typedef unsigned int u32x2 __attribute__((ext_vector_type(2)));

#define AS1 __attribute__((address_space(1)))
#define AS3 __attribute__((address_space(3)))

// fp32 -> bf16 round-to-nearest-even (scalar)
__device__ __forceinline__ u16 f2b(float f) {
  unsigned u = __float_as_uint(f);
  u += 0x7FFFu + ((u >> 16) & 1u);
  return (u16)(u >> 16);
}

// pack two fp32 -> bf16x2 dword (round-half-up; a = low 16, b = high 16)
__device__ __forceinline__ unsigned pkbf(float a, float b) {
  unsigned ua = __float_as_uint(a) + 0x8000u;
  unsigned ub = __float_as_uint(b) + 0x8000u;
  return __builtin_amdgcn_perm(ub, ua, 0x07060302u);
}

__device__ __forceinline__ bf16x8 ldfrag(const u16* p) {
  us8 v = *(const us8*)p;
  return __builtin_bit_cast(bf16x8, v);
}

__device__ __forceinline__ f32x4 mfma16(bf16x8 a, bf16x8 b, f32x4 c) {
  return __builtin_amdgcn_mfma_f32_16x16x32_bf16(a, b, c, 0, 0, 0);
}

// async global->LDS, 16B per lane; lds base must be wave-uniform (lane*16 auto-added)
__device__ __forceinline__ void gl_lds16(const u16* g, AS3 u16* l) {
  __builtin_amdgcn_global_load_lds((AS1 void*)g, (AS3 void*)l, 16, 0, 0);
}

// ---- fp32 -> bf16 cast, 4 elems/thread ----
__global__ __launch_bounds__(256) void cvt_bf16(const float* __restrict__ s,
                                                u16* __restrict__ d, int n4) {
  int i = blockIdx.x * 256 + threadIdx.x;
  if (i >= n4) return;
  f32x4v f = ((const f32x4v*)s)[i];
  us4 o = { f2b(f[0]), f2b(f[1]), f2b(f[2]), f2b(f[3]) };
  ((us4*)d)[i] = o;
}

// ---- GEMM1: C = X @ Wqkv^T -> Q (prescaled by 0.125*log2e), K, Vt (transposed via
// swapped-operand MFMA so stores coalesce). Tile 256x128, block 512, grid (24, 32).
__global__ __launch_bounds__(512, 4) void gemm_qkv(
    const u16* __restrict__ A, const u16* __restrict__ W,
    u16* __restrict__ Qb, u16* __restrict__ Kb, u16* __restrict__ Vt) {
  __shared__ u16 lA[256 * 32];   // 16 KB
  __shared__ u16 lB[128 * 32];   // 8 KB
  const int tid = threadIdx.x;
  const int lane = tid & 63, wave = tid >> 6;
  const int quad = lane >> 4, l16 = lane & 15;
  const int wr = wave >> 1, wc = wave & 1;   // wr 0..3 (64-row strips), wc 0..1
  const int m0 = blockIdx.y * 256;
  const int n0 = blockIdx.x * 128;
  const int sec = n0 >> 10;  // 0=Q 1=K 2=V
  AS3 u16* lA3 = (AS3 u16*)lA;
  AS3 u16* lB3 = (AS3 u16*)lB;
  f32x4 acc[4][4] = {};
  const int ar0 = m0 + (tid >> 2), ac = (tid & 3) * 8;
  const int ar1 = ar0 + 128;
  const int br0 = n0 + (tid >> 2);

  for (int k0 = 0; k0 < 1024; k0 += 32) {
    __syncthreads();
    gl_lds16(A + (size_t)ar0 * 1024 + k0 + ac, lA3 + wave * 512);
    gl_lds16(A + (size_t)ar1 * 1024 + k0 + ac, lA3 + 4096 + wave * 512);
    gl_lds16(W + (size_t)br0 * 1024 + k0 + ac, lB3 + wave * 512);
    __syncthreads();
    bf16x8 aF[4], bF[4];
#pragma unroll
    for (int mt = 0; mt < 4; mt++)
      aF[mt] = ldfrag(&lA[(wr * 64 + mt * 16 + l16) * 32 + quad * 8]);
#pragma unroll
    for (int nt = 0; nt < 4; nt++)
      bF[nt] = ldfrag(&lB[(wc * 64 + nt * 16 + l16) * 32 + quad * 8]);
    if (sec != 2) {
#pragma unroll
      for (int mt = 0; mt < 4; mt++)
#pragma unroll
        for (int nt = 0; nt < 4; nt++)
          acc[mt][nt] = mfma16(aF[mt], bF[nt], acc[mt][nt]);
    } else {  // transposed accumulate: C[n][m]
#pragma unroll
      for (int mt = 0; mt < 4; mt++)
#pragma unroll
        for (int nt = 0; nt < 4; nt++)
          acc[mt][nt] = mfma16(bF[nt], aF[mt], acc[mt][nt]);
    }
  }

  if (sec != 2) {
    const float qs = 0.180336880111120426f;  // 0.125 * log2(e) folded into Q
#pragma unroll
    for (int mt = 0; mt < 4; mt++) {
#pragma unroll
      for (int nt = 0; nt < 4; nt++) {
#pragma unroll
        for (int r = 0; r < 4; r++) {
          float v = acc[mt][nt][r];
          int m = m0 + wr * 64 + mt * 16 + quad * 4 + r;
          int n = n0 + wc * 64 + nt * 16 + l16;
          int ns = n & 1023;
          int h = ns >> 6, e = ns & 63;
          int b = m >> 11, t = m & 2047;
          size_t bh = (size_t)b * 16 + h;
          if (sec == 0) Qb[(bh * 2048 + t) * 64 + e] = f2b(v * qs);
          else          Kb[(bh * 2048 + t) * 64 + e] = f2b(v);
        }
      }
    }
  } else {
#pragma unroll
    for (int mt = 0; mt < 4; mt++) {
#pragma unroll
      for (int nt = 0; nt < 4; nt++) {
#pragma unroll
        for (int r = 0; r < 4; r++) {
          float v = acc[mt][nt][r];
          int n = n0 + wc * 64 + nt * 16 + quad * 4 + r;  // feature (row of C)
          int m = m0 + wr * 64 + mt * 16 + l16;           // token (col of C)
          int ns = n & 1023;
          int h = ns >> 6, e = ns & 63;
          int b = m >> 11, t = m & 2047;
          size_t bh = (size_t)b * 16 + h;
          Vt[(bh * 64 + e) * 2048 + t] = f2b(v);          // lanes -> consecutive t
        }
      }
    }
  }
}

// ---- flash attention v3: transposed S (A=K, B=Q); per-lane softmax state;
// paired Q-tiles (qb, 15-qb) per block -> uniform 17 j-iters/block.
// grid (bh=64, pair=8), block 512 (8 waves).
__global__ __launch_bounds__(512, 4) void attn(
    const u16* __restrict__ Q, const u16* __restrict__ K,
    const u16* __restrict__ Vt, u16* __restrict__ O) {
  __shared__ u16 lK[128 * 72];     // [s][e] pad+8
  __shared__ u16 lV[64 * 136];     // [e][s] pad+8
  __shared__ u16 lP[8 * 16 * 48];  // per-wave [16t][32s pad to 48: bank-balanced, 16B rows]
  const int tid = threadIdx.x;
  const int lane = tid & 63, wave = tid >> 6;
  const int quad = lane >> 4, l16 = lane & 15;
  const int bh = blockIdx.x;
  const int pidx = blockIdx.y;     // 0..7
  const size_t base = (size_t)bh * (2048 * 64);
  u16* lPw = lP + wave * 768;
  const int b = bh >> 4, h = bh & 15;

  for (int half = 0; half < 2; half++) {
    const int qb = half ? pidx : (15 - pidx);   // long tile first
    const int t0 = qb << 7;
    const int tq = t0 + wave * 16 + l16;
    const bf16x8 qF0 = ldfrag(Q + base + (size_t)tq * 64 + quad * 8);
    const bf16x8 qF1 = ldfrag(Q + base + (size_t)tq * 64 + 32 + quad * 8);
    float m_i = -INFINITY, l_i = 0.f;
    f32x4 o[4] = {};

    for (int j = 0; j <= qb; j++) {
      const int s0 = j << 7;
      __syncthreads();
#pragma unroll
      for (int i = 0; i < 2; i++) {  // stage K tile 128x64
        int c = tid + i * 512;
        int r = c >> 3, col = (c & 7) * 8;
        *(us8*)&lK[r * 72 + col] = *(const us8*)(K + base + (size_t)(s0 + r) * 64 + col);
      }
#pragma unroll
      for (int i = 0; i < 2; i++) {  // stage Vt tile 64x128
        int c = tid + i * 512;
        int e = c >> 4, col = (c & 15) * 8;
        *(us8*)&lV[e * 136 + col] = *(const us8*)(Vt + base + (size_t)e * 2048 + s0 + col);
      }
      __syncthreads();

      // S^T = K·Q^T : lane owns col t=tq, rows s = nt*16+quad*4+r  (pre-scaled domain)
      f32x4 S[8];
#pragma unroll
      for (int nt = 0; nt < 8; nt++) {
        int sr = nt * 16 + l16;
        f32x4 a = {};
        a = mfma16(ldfrag(&lK[sr * 72 + quad * 8]), qF0, a);
        a = mfma16(ldfrag(&lK[sr * 72 + 32 + quad * 8]), qF1, a);
        S[nt] = a;
      }

      if (j == qb) {  // causal mask on diagonal tile
#pragma unroll
        for (int nt = 0; nt < 8; nt++)
#pragma unroll
          for (int r = 0; r < 4; r++) {
            int s = s0 + nt * 16 + quad * 4 + r;
            if (s > tq) S[nt][r] = -INFINITY;
          }
      }

      // online softmax: in-lane reduce + 2 cross-half shuffles; exp2 direct
      f32x4 m4 = S[0];
#pragma unroll
      for (int nt = 1; nt < 8; nt++)
#pragma unroll
        for (int r = 0; r < 4; r++) m4[r] = fmaxf(m4[r], S[nt][r]);
      float mx = fmaxf(fmaxf(m4[0], m4[1]), fmaxf(m4[2], m4[3]));
      mx = fmaxf(mx, __shfl_xor(mx, 16));
      mx = fmaxf(mx, __shfl_xor(mx, 32));
      float mn = fmaxf(m_i, mx);
      float alpha = __builtin_amdgcn_exp2f(m_i - mn);
      float sum = 0.f;
#pragma unroll
      for (int nt = 0; nt < 8; nt++)
#pragma unroll
        for (int r = 0; r < 4; r++) {
          float p = __builtin_amdgcn_exp2f(S[nt][r] - mn);
          S[nt][r] = p;
          sum += p;
        }
      sum += __shfl_xor(sum, 16);
      sum += __shfl_xor(sum, 32);
      l_i = l_i * alpha + sum;
      m_i = mn;
#pragma unroll
      for (int ot = 0; ot < 4; ot++)
#pragma unroll
        for (int r = 0; r < 4; r++) o[ot][r] *= alpha;

      // PV per 32-wide s-chunk: P^T through wave-private LDS (in-order DS, no barrier)
#pragma unroll
      for (int c = 0; c < 4; c++) {
        u32x2 d0 = { pkbf(S[2*c][0],   S[2*c][1]),   pkbf(S[2*c][2],   S[2*c][3]) };
        u32x2 d1 = { pkbf(S[2*c+1][0], S[2*c+1][1]), pkbf(S[2*c+1][2], S[2*c+1][3]) };
        *(u32x2*)&lPw[l16 * 48 + quad * 4]      = d0;  // s_local = quad*4+r
        *(u32x2*)&lPw[l16 * 48 + 16 + quad * 4] = d1;  // s_local = 16+quad*4+r
        __asm__ volatile("s_waitcnt lgkmcnt(0)" ::: "memory");
        bf16x8 bP = ldfrag(&lPw[l16 * 48 + quad * 8]);  // B-frag: n=t=l16, k=quad*8+j
#pragma unroll
        for (int ot = 0; ot < 4; ot++)
          o[ot] = mfma16(ldfrag(&lV[(ot * 16 + l16) * 136 + c * 32 + quad * 8]), bP, o[ot]);
      }
    }

    // O^T in C-layout: row e = ot*16+quad*4+r, col t = l16 -> per-lane 8B stores
    const float inv = 1.f / l_i;
#pragma unroll
    for (int ot = 0; ot < 4; ot++) {
      u32x2 pk = { pkbf(o[ot][0] * inv, o[ot][1] * inv),
                   pkbf(o[ot][2] * inv, o[ot][3] * inv) };
      *(u32x2*)&O[((size_t)b * 2048 + tq) * 1024 + h * 64 + ot * 16 + quad * 4] = pk;
    }
  }
}

// ---- GEMM2: out = Ao @ Wo^T + bo, fp32 epilogue. grid (8, 64), block 256.
__global__ __launch_bounds__(256) void gemm_out(
    const u16* __restrict__ A, const u16* __restrict__ W,
    const float* __restrict__ bias, float* __restrict__ out) {
  __shared__ u16 lA[128 * 32];
  __shared__ u16 lB[128 * 32];
  const int tid = threadIdx.x;
  const int lane = tid & 63, wave = tid >> 6;
  const int quad = lane >> 4, l16 = lane & 15;
  const int wr = wave >> 1, wc = wave & 1;
  const int m0 = blockIdx.y * 128;
  const int n0 = blockIdx.x * 128;
  AS3 u16* lA3 = (AS3 u16*)lA;
  AS3 u16* lB3 = (AS3 u16*)lB;
  f32x4 acc[4][4] = {};
  const int c0 = tid, c1 = tid + 256;
  const int ar0 = m0 + (c0 >> 2), ac0 = (c0 & 3) * 8;
  const int ar1 = m0 + (c1 >> 2), ac1 = (c1 & 3) * 8;
  const int br0 = n0 + (c0 >> 2);
  const int br1 = n0 + (c1 >> 2);

  for (int k0 = 0; k0 < 1024; k0 += 32) {
    __syncthreads();
    gl_lds16(A + (size_t)ar0 * 1024 + k0 + ac0, lA3 + wave * 512);
    gl_lds16(A + (size_t)ar1 * 1024 + k0 + ac1, lA3 + 2048 + wave * 512);
    gl_lds16(W + (size_t)br0 * 1024 + k0 + ac0, lB3 + wave * 512);
    gl_lds16(W + (size_t)br1 * 1024 + k0 + ac1, lB3 + 2048 + wave * 512);
    __syncthreads();
    bf16x8 aF[4], bF[4];
#pragma unroll
    for (int mt = 0; mt < 4; mt++)
      aF[mt] = ldfrag(&lA[(wr * 64 + mt * 16 + l16) * 32 + quad * 8]);
#pragma unroll
    for (int nt = 0; nt < 4; nt++)
      bF[nt] = ldfrag(&lB[(wc * 64 + nt * 16 + l16) * 32 + quad * 8]);
#pragma unroll
    for (int mt = 0; mt < 4; mt++)
#pragma unroll
      for (int nt = 0; nt < 4; nt++)
        acc[mt][nt] = mfma16(aF[mt], bF[nt], acc[mt][nt]);
  }

#pragma unroll
  for (int mt = 0; mt < 4; mt++) {
#pragma unroll
    for (int nt = 0; nt < 4; nt++) {
#pragma unroll
      for (int r = 0; r < 4; r++) {
        int m = m0 + wr * 64 + mt * 16 + quad * 4 + r;
        int n = n0 + wc * 64 + nt * 16 + l16;
        out[(size_t)m * 1024 + n] = acc[mt][nt][r] + bias[n];
      }
    }
  }
}

extern "C" void kernel_launch(void* const* d_in, const int* in_sizes, int n_in,
                              void* d_out, int out_size, void* d_ws, size_t ws_size,
                              hipStream_t stream) {
  const float* x  = (const float*)d_in[0];
  const float* Wq = (const float*)d_in[1];
  const float* Wk = (const float*)d_in[2];
  const float* Wv = (const float*)d_in[3];
  const float* Wo = (const float*)d_in[4];
  const float* bo = (const float*)d_in[5];
  float* out = (float*)d_out;

  // ws (u16 elems), 40 MB total: xb/Ao | Wqkv | Wob | Qb.
  // d_out doubles as scratch for Kb+Vt (dead before gemm_out's fp32 write).
  u16* ws   = (u16*)d_ws;
  u16* xb   = ws;
  u16* Wqkv = ws + 8388608;
  u16* Wob  = ws + 11534336;
  u16* Qb   = ws + 12582912;
  u16* Ao   = xb;                       // lifetime-disjoint reuse
  u16* Kb   = (u16*)d_out;
  u16* Vt   = Kb + 8388608;

  cvt_bf16<<<8192, 256, 0, stream>>>(x, xb, 2097152);
  cvt_bf16<<<1024, 256, 0, stream>>>(Wq, Wqkv,            262144);
  cvt_bf16<<<1024, 256, 0, stream>>>(Wk, Wqkv + 1048576,  262144);
  cvt_bf16<<<1024, 256, 0, stream>>>(Wv, Wqkv + 2097152,  262144);
  cvt_bf16<<<1024, 256, 0, stream>>>(Wo, Wob,             262144);

  gemm_qkv<<<dim3(24, 32), 512, 0, stream>>>(xb, Wqkv, Qb, Kb, Vt);
  attn<<<dim3(64, 8), 512, 0, stream>>>(Qb, Kb, Vt, Ao);
  gemm_out<<<dim3(8, 64), 256, 0, stream>>>(Ao, Wob, bo, out);
}

// Round 5
// 305.904 us; speedup vs baseline: 2.4892x; 2.4892x over previous
//
#include <hip/hip_runtime.h>
#include <cstdint>
#include <cstddef>

// ---- types ----
typedef unsigned short u16;
typedef float  f32x4  __attribute__((ext_vector_type(4)));
typedef __bf16 bf16x8 __attribute__((ext_vector_type(8)));
typedef unsigned short us8 __attribute__((ext_vector_type(8)));
typedef unsigned short us4 __attribute__((ext_vector_type(4)));
typedef float  f32x4v __attribute__((ext_vector_type(4)));
typedef unsigned int u32x2 __attribute__((ext_vector_type(2)));

#define AS1 __attribute__((address_space(1)))
#define AS3 __attribute__((address_space(3)))

// fp32 -> bf16 round-to-nearest-even (scalar)
__device__ __forceinline__ u16 f2b(float f) {
  unsigned u = __float_as_uint(f);
  u += 0x7FFFu + ((u >> 16) & 1u);
  return (u16)(u >> 16);
}

// pack two fp32 -> bf16x2 dword (round-half-up; a = low 16, b = high 16)
__device__ __forceinline__ unsigned pkbf(float a, float b) {
  unsigned ua = __float_as_uint(a) + 0x8000u;
  unsigned ub = __float_as_uint(b) + 0x8000u;
  return __builtin_amdgcn_perm(ub, ua, 0x07060302u);
}

__device__ __forceinline__ bf16x8 ldfrag(const u16* p) {
  us8 v = *(const us8*)p;
  return __builtin_bit_cast(bf16x8, v);
}

__device__ __forceinline__ f32x4 mfma16(bf16x8 a, bf16x8 b, f32x4 c) {
  return __builtin_amdgcn_mfma_f32_16x16x32_bf16(a, b, c, 0, 0, 0);
}

// async global->LDS, 16B per lane; lds base must be wave-uniform (lane*16 auto-added)
__device__ __forceinline__ void gl_lds16(const u16* g, AS3 u16* l) {
  __builtin_amdgcn_global_load_lds((AS1 void*)g, (AS3 void*)l, 16, 0, 0);
}

// ---- fp32 -> bf16 cast, 4 elems/thread ----
__global__ __launch_bounds__(256) void cvt_bf16(const float* __restrict__ s,
                                                u16* __restrict__ d, int n4) {
  int i = blockIdx.x * 256 + threadIdx.x;
  if (i >= n4) return;
  f32x4v f = ((const f32x4v*)s)[i];
  us4 o = { f2b(f[0]), f2b(f[1]), f2b(f[2]), f2b(f[3]) };
  ((us4*)d)[i] = o;
}

// ---- GEMM1: C = X @ Wqkv^T -> Q (prescaled by 0.125*log2e), K, Vt (transposed via
// swapped-operand MFMA so stores coalesce). Tile 256x128, block 512, grid (24, 32).
// __launch_bounds__(512, 2): kernel needs ~130 unified VGPR+AGPR regs (64 acc + 32
// frags + addressing). (512,4) capped the budget at 128 -> compiler SPILLED acc to
// scratch -> 2.4 GB/dispatch of HBM scratch traffic, 600 us (R4 post-mortem).
__global__ __launch_bounds__(512, 2) void gemm_qkv(
    const u16* __restrict__ A, const u16* __restrict__ W,
    u16* __restrict__ Qb, u16* __restrict__ Kb, u16* __restrict__ Vt) {
  __shared__ u16 lA[256 * 32];   // 16 KB
  __shared__ u16 lB[128 * 32];   // 8 KB
  const int tid = threadIdx.x;
  const int lane = tid & 63, wave = tid >> 6;
  const int quad = lane >> 4, l16 = lane & 15;
  const int wr = wave >> 1, wc = wave & 1;   // wr 0..3 (64-row strips), wc 0..1
  const int m0 = blockIdx.y * 256;
  const int n0 = blockIdx.x * 128;
  const int sec = n0 >> 10;  // 0=Q 1=K 2=V
  AS3 u16* lA3 = (AS3 u16*)lA;
  AS3 u16* lB3 = (AS3 u16*)lB;
  f32x4 acc[4][4] = {};
  const int ar0 = m0 + (tid >> 2), ac = (tid & 3) * 8;
  const int ar1 = ar0 + 128;
  const int br0 = n0 + (tid >> 2);

  for (int k0 = 0; k0 < 1024; k0 += 32) {
    __syncthreads();
    gl_lds16(A + (size_t)ar0 * 1024 + k0 + ac, lA3 + wave * 512);
    gl_lds16(A + (size_t)ar1 * 1024 + k0 + ac, lA3 + 4096 + wave * 512);
    gl_lds16(W + (size_t)br0 * 1024 + k0 + ac, lB3 + wave * 512);
    __syncthreads();
    bf16x8 aF[4], bF[4];
#pragma unroll
    for (int mt = 0; mt < 4; mt++)
      aF[mt] = ldfrag(&lA[(wr * 64 + mt * 16 + l16) * 32 + quad * 8]);
#pragma unroll
    for (int nt = 0; nt < 4; nt++)
      bF[nt] = ldfrag(&lB[(wc * 64 + nt * 16 + l16) * 32 + quad * 8]);
    if (sec != 2) {
#pragma unroll
      for (int mt = 0; mt < 4; mt++)
#pragma unroll
        for (int nt = 0; nt < 4; nt++)
          acc[mt][nt] = mfma16(aF[mt], bF[nt], acc[mt][nt]);
    } else {  // transposed accumulate: C[n][m]
#pragma unroll
      for (int mt = 0; mt < 4; mt++)
#pragma unroll
        for (int nt = 0; nt < 4; nt++)
          acc[mt][nt] = mfma16(bF[nt], aF[mt], acc[mt][nt]);
    }
  }

  if (sec != 2) {
    const float qs = 0.180336880111120426f;  // 0.125 * log2(e) folded into Q
#pragma unroll
    for (int mt = 0; mt < 4; mt++) {
#pragma unroll
      for (int nt = 0; nt < 4; nt++) {
#pragma unroll
        for (int r = 0; r < 4; r++) {
          float v = acc[mt][nt][r];
          int m = m0 + wr * 64 + mt * 16 + quad * 4 + r;
          int n = n0 + wc * 64 + nt * 16 + l16;
          int ns = n & 1023;
          int h = ns >> 6, e = ns & 63;
          int b = m >> 11, t = m & 2047;
          size_t bh = (size_t)b * 16 + h;
          if (sec == 0) Qb[(bh * 2048 + t) * 64 + e] = f2b(v * qs);
          else          Kb[(bh * 2048 + t) * 64 + e] = f2b(v);
        }
      }
    }
  } else {
#pragma unroll
    for (int mt = 0; mt < 4; mt++) {
#pragma unroll
      for (int nt = 0; nt < 4; nt++) {
#pragma unroll
        for (int r = 0; r < 4; r++) {
          float v = acc[mt][nt][r];
          int n = n0 + wc * 64 + nt * 16 + quad * 4 + r;  // feature (row of C)
          int m = m0 + wr * 64 + mt * 16 + l16;           // token (col of C)
          int ns = n & 1023;
          int h = ns >> 6, e = ns & 63;
          int b = m >> 11, t = m & 2047;
          size_t bh = (size_t)b * 16 + h;
          Vt[(bh * 64 + e) * 2048 + t] = f2b(v);          // lanes -> consecutive t
        }
      }
    }
  }
}

// ---- flash attention v3: transposed S (A=K, B=Q); per-lane softmax state;
// paired Q-tiles (qb, 15-qb) per block -> uniform 17 j-iters/block.
// grid (bh=64, pair=8), block 512 (8 waves).
__global__ __launch_bounds__(512, 4) void attn(
    const u16* __restrict__ Q, const u16* __restrict__ K,
    const u16* __restrict__ Vt, u16* __restrict__ O) {
  __shared__ u16 lK[128 * 72];     // [s][e] pad+8
  __shared__ u16 lV[64 * 136];     // [e][s] pad+8
  __shared__ u16 lP[8 * 16 * 48];  // per-wave [16t][32s pad to 48: bank-balanced, 16B rows]
  const int tid = threadIdx.x;
  const int lane = tid & 63, wave = tid >> 6;
  const int quad = lane >> 4, l16 = lane & 15;
  const int bh = blockIdx.x;
  const int pidx = blockIdx.y;     // 0..7
  const size_t base = (size_t)bh * (2048 * 64);
  u16* lPw = lP + wave * 768;
  const int b = bh >> 4, h = bh & 15;

  for (int half = 0; half < 2; half++) {
    const int qb = half ? pidx : (15 - pidx);   // long tile first
    const int t0 = qb << 7;
    const int tq = t0 + wave * 16 + l16;
    const bf16x8 qF0 = ldfrag(Q + base + (size_t)tq * 64 + quad * 8);
    const bf16x8 qF1 = ldfrag(Q + base + (size_t)tq * 64 + 32 + quad * 8);
    float m_i = -INFINITY, l_i = 0.f;
    f32x4 o[4] = {};

    for (int j = 0; j <= qb; j++) {
      const int s0 = j << 7;
      __syncthreads();
#pragma unroll
      for (int i = 0; i < 2; i++) {  // stage K tile 128x64
        int c = tid + i * 512;
        int r = c >> 3, col = (c & 7) * 8;
        *(us8*)&lK[r * 72 + col] = *(const us8*)(K + base + (size_t)(s0 + r) * 64 + col);
      }
#pragma unroll
      for (int i = 0; i < 2; i++) {  // stage Vt tile 64x128
        int c = tid + i * 512;
        int e = c >> 4, col = (c & 15) * 8;
        *(us8*)&lV[e * 136 + col] = *(const us8*)(Vt + base + (size_t)e * 2048 + s0 + col);
      }
      __syncthreads();

      // S^T = K·Q^T : lane owns col t=tq, rows s = nt*16+quad*4+r  (pre-scaled domain)
      f32x4 S[8];
#pragma unroll
      for (int nt = 0; nt < 8; nt++) {
        int sr = nt * 16 + l16;
        f32x4 a = {};
        a = mfma16(ldfrag(&lK[sr * 72 + quad * 8]), qF0, a);
        a = mfma16(ldfrag(&lK[sr * 72 + 32 + quad * 8]), qF1, a);
        S[nt] = a;
      }

      if (j == qb) {  // causal mask on diagonal tile
#pragma unroll
        for (int nt = 0; nt < 8; nt++)
#pragma unroll
          for (int r = 0; r < 4; r++) {
            int s = s0 + nt * 16 + quad * 4 + r;
            if (s > tq) S[nt][r] = -INFINITY;
          }
      }

      // online softmax: in-lane reduce + 2 cross-half shuffles; exp2 direct
      f32x4 m4 = S[0];
#pragma unroll
      for (int nt = 1; nt < 8; nt++)
#pragma unroll
        for (int r = 0; r < 4; r++) m4[r] = fmaxf(m4[r], S[nt][r]);
      float mx = fmaxf(fmaxf(m4[0], m4[1]), fmaxf(m4[2], m4[3]));
      mx = fmaxf(mx, __shfl_xor(mx, 16));
      mx = fmaxf(mx, __shfl_xor(mx, 32));
      float mn = fmaxf(m_i, mx);
      float alpha = __builtin_amdgcn_exp2f(m_i - mn);
      float sum = 0.f;
#pragma unroll
      for (int nt = 0; nt < 8; nt++)
#pragma unroll
        for (int r = 0; r < 4; r++) {
          float p = __builtin_amdgcn_exp2f(S[nt][r] - mn);
          S[nt][r] = p;
          sum += p;
        }
      sum += __shfl_xor(sum, 16);
      sum += __shfl_xor(sum, 32);
      l_i = l_i * alpha + sum;
      m_i = mn;
#pragma unroll
      for (int ot = 0; ot < 4; ot++)
#pragma unroll
        for (int r = 0; r < 4; r++) o[ot][r] *= alpha;

      // PV per 32-wide s-chunk: P^T through wave-private LDS (in-order DS, no barrier)
#pragma unroll
      for (int c = 0; c < 4; c++) {
        u32x2 d0 = { pkbf(S[2*c][0],   S[2*c][1]),   pkbf(S[2*c][2],   S[2*c][3]) };
        u32x2 d1 = { pkbf(S[2*c+1][0], S[2*c+1][1]), pkbf(S[2*c+1][2], S[2*c+1][3]) };
        *(u32x2*)&lPw[l16 * 48 + quad * 4]      = d0;  // s_local = quad*4+r
        *(u32x2*)&lPw[l16 * 48 + 16 + quad * 4] = d1;  // s_local = 16+quad*4+r
        __asm__ volatile("s_waitcnt lgkmcnt(0)" ::: "memory");
        bf16x8 bP = ldfrag(&lPw[l16 * 48 + quad * 8]);  // B-frag: n=t=l16, k=quad*8+j
#pragma unroll
        for (int ot = 0; ot < 4; ot++)
          o[ot] = mfma16(ldfrag(&lV[(ot * 16 + l16) * 136 + c * 32 + quad * 8]), bP, o[ot]);
      }
    }

    // O^T in C-layout: row e = ot*16+quad*4+r, col t = l16 -> per-lane 8B stores
    const float inv = 1.f / l_i;
#pragma unroll
    for (int ot = 0; ot < 4; ot++) {
      u32x2 pk = { pkbf(o[ot][0] * inv, o[ot][1] * inv),
                   pkbf(o[ot][2] * inv, o[ot][3] * inv) };
      *(u32x2*)&O[((size_t)b * 2048 + tq) * 1024 + h * 64 + ot * 16 + quad * 4] = pk;
    }
  }
}

// ---- GEMM2: out = Ao @ Wo^T + bo, fp32 epilogue. grid (8, 64), block 256.
__global__ __launch_bounds__(256) void gemm_out(
    const u16* __restrict__ A, const u16* __restrict__ W,
    const float* __restrict__ bias, float* __restrict__ out) {
  __shared__ u16 lA[128 * 32];
  __shared__ u16 lB[128 * 32];
  const int tid = threadIdx.x;
  const int lane = tid & 63, wave = tid >> 6;
  const int quad = lane >> 4, l16 = lane & 15;
  const int wr = wave >> 1, wc = wave & 1;
  const int m0 = blockIdx.y * 128;
  const int n0 = blockIdx.x * 128;
  AS3 u16* lA3 = (AS3 u16*)lA;
  AS3 u16* lB3 = (AS3 u16*)lB;
  f32x4 acc[4][4] = {};
  const int c0 = tid, c1 = tid + 256;
  const int ar0 = m0 + (c0 >> 2), ac0 = (c0 & 3) * 8;
  const int ar1 = m0 + (c1 >> 2), ac1 = (c1 & 3) * 8;
  const int br0 = n0 + (c0 >> 2);
  const int br1 = n0 + (c1 >> 2);

  for (int k0 = 0; k0 < 1024; k0 += 32) {
    __syncthreads();
    gl_lds16(A + (size_t)ar0 * 1024 + k0 + ac0, lA3 + wave * 512);
    gl_lds16(A + (size_t)ar1 * 1024 + k0 + ac1, lA3 + 2048 + wave * 512);
    gl_lds16(W + (size_t)br0 * 1024 + k0 + ac0, lB3 + wave * 512);
    gl_lds16(W + (size_t)br1 * 1024 + k0 + ac1, lB3 + 2048 + wave * 512);
    __syncthreads();
    bf16x8 aF[4], bF[4];
#pragma unroll
    for (int mt = 0; mt < 4; mt++)
      aF[mt] = ldfrag(&lA[(wr * 64 + mt * 16 + l16) * 32 + quad * 8]);
#pragma unroll
    for (int nt = 0; nt < 4; nt++)
      bF[nt] = ldfrag(&lB[(wc * 64 + nt * 16 + l16) * 32 + quad * 8]);
#pragma unroll
    for (int mt = 0; mt < 4; mt++)
#pragma unroll
      for (int nt = 0; nt < 4; nt++)
        acc[mt][nt] = mfma16(aF[mt], bF[nt], acc[mt][nt]);
  }

#pragma unroll
  for (int mt = 0; mt < 4; mt++) {
#pragma unroll
    for (int nt = 0; nt < 4; nt++) {
#pragma unroll
      for (int r = 0; r < 4; r++) {
        int m = m0 + wr * 64 + mt * 16 + quad * 4 + r;
        int n = n0 + wc * 64 + nt * 16 + l16;
        out[(size_t)m * 1024 + n] = acc[mt][nt][r] + bias[n];
      }
    }
  }
}

extern "C" void kernel_launch(void* const* d_in, const int* in_sizes, int n_in,
                              void* d_out, int out_size, void* d_ws, size_t ws_size,
                              hipStream_t stream) {
  const float* x  = (const float*)d_in[0];
  const float* Wq = (const float*)d_in[1];
  const float* Wk = (const float*)d_in[2];
  const float* Wv = (const float*)d_in[3];
  const float* Wo = (const float*)d_in[4];
  const float* bo = (const float*)d_in[5];
  float* out = (float*)d_out;

  // ws (u16 elems), 40 MB total: xb/Ao | Wqkv | Wob | Qb.
  // d_out doubles as scratch for Kb+Vt (dead before gemm_out's fp32 write).
  u16* ws   = (u16*)d_ws;
  u16* xb   = ws;
  u16* Wqkv = ws + 8388608;
  u16* Wob  = ws + 11534336;
  u16* Qb   = ws + 12582912;
  u16* Ao   = xb;                       // lifetime-disjoint reuse
  u16* Kb   = (u16*)d_out;
  u16* Vt   = Kb + 8388608;

  cvt_bf16<<<8192, 256, 0, stream>>>(x, xb, 2097152);
  cvt_bf16<<<1024, 256, 0, stream>>>(Wq, Wqkv,            262144);
  cvt_bf16<<<1024, 256, 0, stream>>>(Wk, Wqkv + 1048576,  262144);
  cvt_bf16<<<1024, 256, 0, stream>>>(Wv, Wqkv + 2097152,  262144);
  cvt_bf16<<<1024, 256, 0, stream>>>(Wo, Wob,             262144);

  gemm_qkv<<<dim3(24, 32), 512, 0, stream>>>(xb, Wqkv, Qb, Kb, Vt);
  attn<<<dim3(64, 8), 512, 0, stream>>>(Qb, Kb, Vt, Ao);
  gemm_out<<<dim3(8, 64), 256, 0, stream>>>(Ao, Wob, bo, out);
}

// Round 6
// 295.949 us; speedup vs baseline: 2.5729x; 1.0336x over previous
//
#include <hip/hip_runtime.h>
#include <cstdint>
#include <cstddef>

// ---- types ----
typedef unsigned short u16;
typedef float  f32x4  __attribute__((ext_vector_type(4)));
typedef __bf16 bf16x8 __attribute__((ext_vector_type(8)));
typedef unsigned short us8 __attribute__((ext_vector_type(8)));
typedef unsigned short us4 __attribute__((ext_vector_type(4)));
typedef float  f32x4v __attribute__((ext_vector_type(4)));
typedef unsigned int u32x2 __attribute__((ext_vector_type(2)));

#define AS1 __attribute__((address_space(1)))
#define AS3 __attribute__((address_space(3)))

// fp32 -> bf16 round-to-nearest-even (scalar)
__device__ __forceinline__ u16 f2b(float f) {
  unsigned u = __float_as_uint(f);
  u += 0x7FFFu + ((u >> 16) & 1u);
  return (u16)(u >> 16);
}

// pack two fp32 -> bf16x2 dword (round-half-up; a = low 16, b = high 16)
__device__ __forceinline__ unsigned pkbf(float a, float b) {
  unsigned ua = __float_as_uint(a) + 0x8000u;
  unsigned ub = __float_as_uint(b) + 0x8000u;
  return __builtin_amdgcn_perm(ub, ua, 0x07060302u);
}

__device__ __forceinline__ bf16x8 ldfrag(const u16* p) {
  us8 v = *(const us8*)p;
  return __builtin_bit_cast(bf16x8, v);
}

__device__ __forceinline__ f32x4 mfma16(bf16x8 a, bf16x8 b, f32x4 c) {
  return __builtin_amdgcn_mfma_f32_16x16x32_bf16(a, b, c, 0, 0, 0);
}

// async global->LDS, 16B per lane; lds base must be wave-uniform (lane*16 auto-added)
__device__ __forceinline__ void gl_lds16(const u16* g, AS3 u16* l) {
  __builtin_amdgcn_global_load_lds((AS1 void*)g, (AS3 void*)l, 16, 0, 0);
}

// XOR-swizzled LDS tile layout (rows of 32 u16 = four 16B granules, 16-row chunks):
//   position(row r, granule g) = r*4 + (g ^ ((r>>1)&3))   [granules within chunk]
// Staging lane L (writes chunkBase + L*16B) must source granule (L&3)^((L>>3)&3)
// of row L>>2; then position == L. Readers use quad -> quad ^ ((l16>>1)&3).
// Result: the 16 rows a quad reads start in all 8 4-bank groups (2 lanes/bank =
// conflict-free, m136) instead of 2 groups (8-way conflict: R5's 6.29e6 counter).

// ---- fp32 -> bf16 cast, 4 elems/thread ----
__global__ __launch_bounds__(256) void cvt_bf16(const float* __restrict__ s,
                                                u16* __restrict__ d, int n4) {
  int i = blockIdx.x * 256 + threadIdx.x;
  if (i >= n4) return;
  f32x4v f = ((const f32x4v*)s)[i];
  us4 o = { f2b(f[0]), f2b(f[1]), f2b(f[2]), f2b(f[3]) };
  ((us4*)d)[i] = o;
}

// ---- GEMM1: C = X @ Wqkv^T -> Q (prescaled by 0.125*log2e), K, Vt (transposed via
// swapped-operand MFMA so stores coalesce). Tile 256x128, block 512, grid (24, 32).
// __launch_bounds__(512, 2): ~130 unified regs needed; (512,4) forced acc spill (R4).
__global__ __launch_bounds__(512, 2) void gemm_qkv(
    const u16* __restrict__ A, const u16* __restrict__ W,
    u16* __restrict__ Qb, u16* __restrict__ Kb, u16* __restrict__ Vt) {
  __shared__ u16 lA[256 * 32];   // 16 KB
  __shared__ u16 lB[128 * 32];   // 8 KB
  const int tid = threadIdx.x;
  const int lane = tid & 63, wave = tid >> 6;
  const int quad = lane >> 4, l16 = lane & 15;
  const int wr = wave >> 1, wc = wave & 1;   // wr 0..3 (64-row strips), wc 0..1
  const int m0 = blockIdx.y * 256;
  const int n0 = blockIdx.x * 128;
  const int sec = n0 >> 10;  // 0=Q 1=K 2=V
  AS3 u16* lA3 = (AS3 u16*)lA;
  AS3 u16* lB3 = (AS3 u16*)lB;
  f32x4 acc[4][4] = {};
  const int swg = (((tid & 3) ^ ((tid >> 3) & 3)) * 8);  // swizzled source granule col
  const int qsw = (quad ^ ((l16 >> 1) & 3)) * 8;         // swizzled reader granule col
  const int ar0 = m0 + (tid >> 2);
  const int ar1 = ar0 + 128;
  const int br0 = n0 + (tid >> 2);

  for (int k0 = 0; k0 < 1024; k0 += 32) {
    __syncthreads();
    gl_lds16(A + (size_t)ar0 * 1024 + k0 + swg, lA3 + wave * 512);
    gl_lds16(A + (size_t)ar1 * 1024 + k0 + swg, lA3 + 4096 + wave * 512);
    gl_lds16(W + (size_t)br0 * 1024 + k0 + swg, lB3 + wave * 512);
    __syncthreads();
    bf16x8 aF[4], bF[4];
#pragma unroll
    for (int mt = 0; mt < 4; mt++)
      aF[mt] = ldfrag(&lA[(wr * 64 + mt * 16 + l16) * 32 + qsw]);
#pragma unroll
    for (int nt = 0; nt < 4; nt++)
      bF[nt] = ldfrag(&lB[(wc * 64 + nt * 16 + l16) * 32 + qsw]);
    if (sec != 2) {
#pragma unroll
      for (int mt = 0; mt < 4; mt++)
#pragma unroll
        for (int nt = 0; nt < 4; nt++)
          acc[mt][nt] = mfma16(aF[mt], bF[nt], acc[mt][nt]);
    } else {  // transposed accumulate: C[n][m]
#pragma unroll
      for (int mt = 0; mt < 4; mt++)
#pragma unroll
        for (int nt = 0; nt < 4; nt++)
          acc[mt][nt] = mfma16(bF[nt], aF[mt], acc[mt][nt]);
    }
  }

  if (sec != 2) {
    const float qs = 0.180336880111120426f;  // 0.125 * log2(e) folded into Q
#pragma unroll
    for (int mt = 0; mt < 4; mt++) {
#pragma unroll
      for (int nt = 0; nt < 4; nt++) {
#pragma unroll
        for (int r = 0; r < 4; r++) {
          float v = acc[mt][nt][r];
          int m = m0 + wr * 64 + mt * 16 + quad * 4 + r;
          int n = n0 + wc * 64 + nt * 16 + l16;
          int ns = n & 1023;
          int h = ns >> 6, e = ns & 63;
          int b = m >> 11, t = m & 2047;
          size_t bh = (size_t)b * 16 + h;
          if (sec == 0) Qb[(bh * 2048 + t) * 64 + e] = f2b(v * qs);
          else          Kb[(bh * 2048 + t) * 64 + e] = f2b(v);
        }
      }
    }
  } else {
#pragma unroll
    for (int mt = 0; mt < 4; mt++) {
#pragma unroll
      for (int nt = 0; nt < 4; nt++) {
#pragma unroll
        for (int r = 0; r < 4; r++) {
          float v = acc[mt][nt][r];
          int n = n0 + wc * 64 + nt * 16 + quad * 4 + r;  // feature (row of C)
          int m = m0 + wr * 64 + mt * 16 + l16;           // token (col of C)
          int ns = n & 1023;
          int h = ns >> 6, e = ns & 63;
          int b = m >> 11, t = m & 2047;
          size_t bh = (size_t)b * 16 + h;
          Vt[(bh * 64 + e) * 2048 + t] = f2b(v);          // lanes -> consecutive t
        }
      }
    }
  }
}

// ---- flash attention v3: transposed S (A=K, B=Q); per-lane softmax state;
// paired Q-tiles (qb, 15-qb) per block -> uniform 17 j-iters/block.
// grid (bh=64, pair=8), block 512 (8 waves). lK/lV strides (72/136 u16) already
// rotate bank starts by 4 dwords/row -> conflict-free b128 reads.
__global__ __launch_bounds__(512, 4) void attn(
    const u16* __restrict__ Q, const u16* __restrict__ K,
    const u16* __restrict__ Vt, u16* __restrict__ O) {
  __shared__ u16 lK[128 * 72];     // [s][e] pad+8
  __shared__ u16 lV[64 * 136];     // [e][s] pad+8
  __shared__ u16 lP[8 * 16 * 48];  // per-wave [16t][32s pad to 48]
  const int tid = threadIdx.x;
  const int lane = tid & 63, wave = tid >> 6;
  const int quad = lane >> 4, l16 = lane & 15;
  const int bh = blockIdx.x;
  const int pidx = blockIdx.y;     // 0..7
  const size_t base = (size_t)bh * (2048 * 64);
  u16* lPw = lP + wave * 768;
  const int b = bh >> 4, h = bh & 15;

  for (int half = 0; half < 2; half++) {
    const int qb = half ? pidx : (15 - pidx);   // long tile first
    const int t0 = qb << 7;
    const int tq = t0 + wave * 16 + l16;
    const bf16x8 qF0 = ldfrag(Q + base + (size_t)tq * 64 + quad * 8);
    const bf16x8 qF1 = ldfrag(Q + base + (size_t)tq * 64 + 32 + quad * 8);
    float m_i = -INFINITY, l_i = 0.f;
    f32x4 o[4] = {};

    for (int j = 0; j <= qb; j++) {
      const int s0 = j << 7;
      __syncthreads();
#pragma unroll
      for (int i = 0; i < 2; i++) {  // stage K tile 128x64
        int c = tid + i * 512;
        int r = c >> 3, col = (c & 7) * 8;
        *(us8*)&lK[r * 72 + col] = *(const us8*)(K + base + (size_t)(s0 + r) * 64 + col);
      }
#pragma unroll
      for (int i = 0; i < 2; i++) {  // stage Vt tile 64x128
        int c = tid + i * 512;
        int e = c >> 4, col = (c & 15) * 8;
        *(us8*)&lV[e * 136 + col] = *(const us8*)(Vt + base + (size_t)e * 2048 + s0 + col);
      }
      __syncthreads();

      // S^T = K·Q^T : lane owns col t=tq, rows s = nt*16+quad*4+r  (pre-scaled domain)
      f32x4 S[8];
#pragma unroll
      for (int nt = 0; nt < 8; nt++) {
        int sr = nt * 16 + l16;
        f32x4 a = {};
        a = mfma16(ldfrag(&lK[sr * 72 + quad * 8]), qF0, a);
        a = mfma16(ldfrag(&lK[sr * 72 + 32 + quad * 8]), qF1, a);
        S[nt] = a;
      }

      if (j == qb) {  // causal mask on diagonal tile
#pragma unroll
        for (int nt = 0; nt < 8; nt++)
#pragma unroll
          for (int r = 0; r < 4; r++) {
            int s = s0 + nt * 16 + quad * 4 + r;
            if (s > tq) S[nt][r] = -INFINITY;
          }
      }

      // online softmax: in-lane reduce + 2 cross-half shuffles; exp2 direct
      f32x4 m4 = S[0];
#pragma unroll
      for (int nt = 1; nt < 8; nt++)
#pragma unroll
        for (int r = 0; r < 4; r++) m4[r] = fmaxf(m4[r], S[nt][r]);
      float mx = fmaxf(fmaxf(m4[0], m4[1]), fmaxf(m4[2], m4[3]));
      mx = fmaxf(mx, __shfl_xor(mx, 16));
      mx = fmaxf(mx, __shfl_xor(mx, 32));
      float mn = fmaxf(m_i, mx);
      float alpha = __builtin_amdgcn_exp2f(m_i - mn);
      float sum = 0.f;
#pragma unroll
      for (int nt = 0; nt < 8; nt++)
#pragma unroll
        for (int r = 0; r < 4; r++) {
          float p = __builtin_amdgcn_exp2f(S[nt][r] - mn);
          S[nt][r] = p;
          sum += p;
        }
      sum += __shfl_xor(sum, 16);
      sum += __shfl_xor(sum, 32);
      l_i = l_i * alpha + sum;
      m_i = mn;
#pragma unroll
      for (int ot = 0; ot < 4; ot++)
#pragma unroll
        for (int r = 0; r < 4; r++) o[ot][r] *= alpha;

      // PV per 32-wide s-chunk: P^T through wave-private LDS (in-order DS, no barrier)
#pragma unroll
      for (int c = 0; c < 4; c++) {
        u32x2 d0 = { pkbf(S[2*c][0],   S[2*c][1]),   pkbf(S[2*c][2],   S[2*c][3]) };
        u32x2 d1 = { pkbf(S[2*c+1][0], S[2*c+1][1]), pkbf(S[2*c+1][2], S[2*c+1][3]) };
        *(u32x2*)&lPw[l16 * 48 + quad * 4]      = d0;  // s_local = quad*4+r
        *(u32x2*)&lPw[l16 * 48 + 16 + quad * 4] = d1;  // s_local = 16+quad*4+r
        __asm__ volatile("s_waitcnt lgkmcnt(0)" ::: "memory");
        bf16x8 bP = ldfrag(&lPw[l16 * 48 + quad * 8]);  // B-frag: n=t=l16, k=quad*8+j
#pragma unroll
        for (int ot = 0; ot < 4; ot++)
          o[ot] = mfma16(ldfrag(&lV[(ot * 16 + l16) * 136 + c * 32 + quad * 8]), bP, o[ot]);
      }
    }

    // O^T in C-layout: row e = ot*16+quad*4+r, col t = l16 -> per-lane 8B stores
    const float inv = 1.f / l_i;
#pragma unroll
    for (int ot = 0; ot < 4; ot++) {
      u32x2 pk = { pkbf(o[ot][0] * inv, o[ot][1] * inv),
                   pkbf(o[ot][2] * inv, o[ot][3] * inv) };
      *(u32x2*)&O[((size_t)b * 2048 + tq) * 1024 + h * 64 + ot * 16 + quad * 4] = pk;
    }
  }
}

// ---- GEMM2: out = Ao @ Wo^T + bo, fp32 epilogue. grid (8, 64), block 256.
__global__ __launch_bounds__(256) void gemm_out(
    const u16* __restrict__ A, const u16* __restrict__ W,
    const float* __restrict__ bias, float* __restrict__ out) {
  __shared__ u16 lA[128 * 32];
  __shared__ u16 lB[128 * 32];
  const int tid = threadIdx.x;
  const int lane = tid & 63, wave = tid >> 6;
  const int quad = lane >> 4, l16 = lane & 15;
  const int wr = wave >> 1, wc = wave & 1;
  const int m0 = blockIdx.y * 128;
  const int n0 = blockIdx.x * 128;
  AS3 u16* lA3 = (AS3 u16*)lA;
  AS3 u16* lB3 = (AS3 u16*)lB;
  f32x4 acc[4][4] = {};
  const int swg = (((tid & 3) ^ ((tid >> 3) & 3)) * 8);  // swizzled source granule col
  const int qsw = (quad ^ ((l16 >> 1) & 3)) * 8;         // swizzled reader granule col
  const int c0 = tid, c1 = tid + 256;
  const int ar0 = m0 + (c0 >> 2);
  const int ar1 = m0 + (c1 >> 2);
  const int br0 = n0 + (c0 >> 2);
  const int br1 = n0 + (c1 >> 2);

  for (int k0 = 0; k0 < 1024; k0 += 32) {
    __syncthreads();
    gl_lds16(A + (size_t)ar0 * 1024 + k0 + swg, lA3 + wave * 512);
    gl_lds16(A + (size_t)ar1 * 1024 + k0 + swg, lA3 + 2048 + wave * 512);
    gl_lds16(W + (size_t)br0 * 1024 + k0 + swg, lB3 + wave * 512);
    gl_lds16(W + (size_t)br1 * 1024 + k0 + swg, lB3 + 2048 + wave * 512);
    __syncthreads();
    bf16x8 aF[4], bF[4];
#pragma unroll
    for (int mt = 0; mt < 4; mt++)
      aF[mt] = ldfrag(&lA[(wr * 64 + mt * 16 + l16) * 32 + qsw]);
#pragma unroll
    for (int nt = 0; nt < 4; nt++)
      bF[nt] = ldfrag(&lB[(wc * 64 + nt * 16 + l16) * 32 + qsw]);
#pragma unroll
    for (int mt = 0; mt < 4; mt++)
#pragma unroll
      for (int nt = 0; nt < 4; nt++)
        acc[mt][nt] = mfma16(aF[mt], bF[nt], acc[mt][nt]);
  }

#pragma unroll
  for (int mt = 0; mt < 4; mt++) {
#pragma unroll
    for (int nt = 0; nt < 4; nt++) {
#pragma unroll
      for (int r = 0; r < 4; r++) {
        int m = m0 + wr * 64 + mt * 16 + quad * 4 + r;
        int n = n0 + wc * 64 + nt * 16 + l16;
        out[(size_t)m * 1024 + n] = acc[mt][nt][r] + bias[n];
      }
    }
  }
}

extern "C" void kernel_launch(void* const* d_in, const int* in_sizes, int n_in,
                              void* d_out, int out_size, void* d_ws, size_t ws_size,
                              hipStream_t stream) {
  const float* x  = (const float*)d_in[0];
  const float* Wq = (const float*)d_in[1];
  const float* Wk = (const float*)d_in[2];
  const float* Wv = (const float*)d_in[3];
  const float* Wo = (const float*)d_in[4];
  const float* bo = (const float*)d_in[5];
  float* out = (float*)d_out;

  // ws (u16 elems), 40 MB total: xb/Ao | Wqkv | Wob | Qb.
  // d_out doubles as scratch for Kb+Vt (dead before gemm_out's fp32 write).
  u16* ws   = (u16*)d_ws;
  u16* xb   = ws;
  u16* Wqkv = ws + 8388608;
  u16* Wob  = ws + 11534336;
  u16* Qb   = ws + 12582912;
  u16* Ao   = xb;                       // lifetime-disjoint reuse
  u16* Kb   = (u16*)d_out;
  u16* Vt   = Kb + 8388608;

  cvt_bf16<<<8192, 256, 0, stream>>>(x, xb, 2097152);
  cvt_bf16<<<1024, 256, 0, stream>>>(Wq, Wqkv,            262144);
  cvt_bf16<<<1024, 256, 0, stream>>>(Wk, Wqkv + 1048576,  262144);
  cvt_bf16<<<1024, 256, 0, stream>>>(Wv, Wqkv + 2097152,  262144);
  cvt_bf16<<<1024, 256, 0, stream>>>(Wo, Wob,             262144);

  gemm_qkv<<<dim3(24, 32), 512, 0, stream>>>(xb, Wqkv, Qb, Kb, Vt);
  attn<<<dim3(64, 8), 512, 0, stream>>>(Qb, Kb, Vt, Ao);
  gemm_out<<<dim3(8, 64), 256, 0, stream>>>(Ao, Wob, bo, out);
}

// Round 7
// 289.938 us; speedup vs baseline: 2.6262x; 1.0207x over previous
//
#include <hip/hip_runtime.h>
#include <cstdint>
#include <cstddef>

// ---- types ----
typedef unsigned short u16;
typedef float  f32x4  __attribute__((ext_vector_type(4)));
typedef __bf16 bf16x8 __attribute__((ext_vector_type(8)));
typedef unsigned short us8 __attribute__((ext_vector_type(8)));
typedef unsigned short us4 __attribute__((ext_vector_type(4)));
typedef float  f32x4v __attribute__((ext_vector_type(4)));
typedef unsigned int u32x2 __attribute__((ext_vector_type(2)));

#define AS1 __attribute__((address_space(1)))
#define AS3 __attribute__((address_space(3)))

// fp32 -> bf16 round-to-nearest-even (scalar)
__device__ __forceinline__ u16 f2b(float f) {
  unsigned u = __float_as_uint(f);
  u += 0x7FFFu + ((u >> 16) & 1u);
  return (u16)(u >> 16);
}

// pack two fp32 -> bf16x2 dword (round-half-up; a = low 16, b = high 16)
__device__ __forceinline__ unsigned pkbf(float a, float b) {
  unsigned ua = __float_as_uint(a) + 0x8000u;
  unsigned ub = __float_as_uint(b) + 0x8000u;
  return __builtin_amdgcn_perm(ub, ua, 0x07060302u);
}

__device__ __forceinline__ bf16x8 ldfrag(const u16* p) {
  us8 v = *(const us8*)p;
  return __builtin_bit_cast(bf16x8, v);
}

__device__ __forceinline__ f32x4 mfma16(bf16x8 a, bf16x8 b, f32x4 c) {
  return __builtin_amdgcn_mfma_f32_16x16x32_bf16(a, b, c, 0, 0, 0);
}

// async global->LDS, 16B per lane; lds base must be wave-uniform (lane*16 auto-added)
__device__ __forceinline__ void gl_lds16(const u16* g, AS3 u16* l) {
  __builtin_amdgcn_global_load_lds((AS1 void*)g, (AS3 void*)l, 16, 0, 0);
}

// XOR-swizzled LDS tile layout (rows of 32 u16 = four 16B granules, 16-row chunks):
//   position(row r, granule g) = r*4 + (g ^ ((r>>1)&3))
// Staging lane L sources granule (L&3)^((L>>3)&3) so position == L (wave-uniform
// base + lane*16 stays legal for global_load_lds). Readers: quad ^ ((l16>>1)&3).
// R6: conflicts 6.29e6 -> 0.

// ---- fp32 -> bf16 cast, 4 elems/thread ----
__global__ __launch_bounds__(256) void cvt_bf16(const float* __restrict__ s,
                                                u16* __restrict__ d, int n4) {
  int i = blockIdx.x * 256 + threadIdx.x;
  if (i >= n4) return;
  f32x4v f = ((const f32x4v*)s)[i];
  us4 o = { f2b(f[0]), f2b(f[1]), f2b(f[2]), f2b(f[3]) };
  ((us4*)d)[i] = o;
}

// ---- fused weight cast: 4 weight tensors in one launch (grid (1024, 4)) ----
__global__ __launch_bounds__(256) void cvt_w(
    const float* __restrict__ Wq, const float* __restrict__ Wk,
    const float* __restrict__ Wv, const float* __restrict__ Wo,
    u16* __restrict__ Wqkv, u16* __restrict__ Wob) {
  const float* s;
  u16* d;
  switch (blockIdx.y) {
    case 0: s = Wq; d = Wqkv;           break;
    case 1: s = Wk; d = Wqkv + 1048576; break;
    case 2: s = Wv; d = Wqkv + 2097152; break;
    default: s = Wo; d = Wob;           break;
  }
  int i = blockIdx.x * 256 + threadIdx.x;  // < 262144 always (1024 blocks x 256)
  f32x4v f = ((const f32x4v*)s)[i];
  us4 o = { f2b(f[0]), f2b(f[1]), f2b(f[2]), f2b(f[3]) };
  ((us4*)d)[i] = o;
}

// ---- GEMM1: C = X @ Wqkv^T -> Q (prescaled by 0.125*log2e), K, Vt (transposed via
// swapped-operand MFMA so stores coalesce). Tile 256x128, block 512, grid (24, 32).
// 1 block/CU resident (156 unified regs/wave) -> staging latency fully exposed at
// the barrier (R6: ~2400 cyc/k-iter vs ~400 compute). Fix: explicit LDS double
// buffer — issue next tile's global_load_lds before computing current; the next
// barrier's vmcnt(0) drain then lands after a full compute phase of flight time.
__global__ __launch_bounds__(512, 2) void gemm_qkv(
    const u16* __restrict__ A, const u16* __restrict__ W,
    u16* __restrict__ Qb, u16* __restrict__ Kb, u16* __restrict__ Vt) {
  __shared__ u16 lA[2][256 * 32];   // 2 x 16 KB
  __shared__ u16 lB[2][128 * 32];   // 2 x 8 KB
  const int tid = threadIdx.x;
  const int lane = tid & 63, wave = tid >> 6;
  const int quad = lane >> 4, l16 = lane & 15;
  const int wr = wave >> 1, wc = wave & 1;   // wr 0..3 (64-row strips), wc 0..1
  const int m0 = blockIdx.y * 256;
  const int n0 = blockIdx.x * 128;
  const int sec = n0 >> 10;  // 0=Q 1=K 2=V
  AS3 u16* lA3 = (AS3 u16*)lA;
  AS3 u16* lB3 = (AS3 u16*)lB;
  f32x4 acc[4][4] = {};
  const int swg = (((tid & 3) ^ ((tid >> 3) & 3)) * 8);  // swizzled source granule col
  const int qsw = (quad ^ ((l16 >> 1) & 3)) * 8;         // swizzled reader granule col
  const int ar0 = m0 + (tid >> 2);
  const int ar1 = ar0 + 128;
  const int br0 = n0 + (tid >> 2);

  const u16* gA0 = A + (size_t)ar0 * 1024 + swg;
  const u16* gA1 = A + (size_t)ar1 * 1024 + swg;
  const u16* gB0 = W + (size_t)br0 * 1024 + swg;

  // prologue: stage k0=0 into buf 0
  gl_lds16(gA0, lA3 + wave * 512);
  gl_lds16(gA1, lA3 + 4096 + wave * 512);
  gl_lds16(gB0, lB3 + wave * 512);

  int buf = 0;
  for (int k0 = 0; k0 < 1024; k0 += 32, buf ^= 1) {
    __syncthreads();  // drains buf's loads (issued one iter ago, flew during compute)
    if (k0 + 32 < 1024) {  // issue next tile into buf^1
      int kn = k0 + 32;
      int bo = (buf ^ 1) * 8192;
      int bo2 = (buf ^ 1) * 4096;
      gl_lds16(gA0 + kn, lA3 + bo + wave * 512);
      gl_lds16(gA1 + kn, lA3 + bo + 4096 + wave * 512);
      gl_lds16(gB0 + kn, lB3 + bo2 + wave * 512);
    }
    bf16x8 aF[4], bF[4];
#pragma unroll
    for (int mt = 0; mt < 4; mt++)
      aF[mt] = ldfrag(&lA[buf][(wr * 64 + mt * 16 + l16) * 32 + qsw]);
#pragma unroll
    for (int nt = 0; nt < 4; nt++)
      bF[nt] = ldfrag(&lB[buf][(wc * 64 + nt * 16 + l16) * 32 + qsw]);
    if (sec != 2) {
#pragma unroll
      for (int mt = 0; mt < 4; mt++)
#pragma unroll
        for (int nt = 0; nt < 4; nt++)
          acc[mt][nt] = mfma16(aF[mt], bF[nt], acc[mt][nt]);
    } else {  // transposed accumulate: C[n][m]
#pragma unroll
      for (int mt = 0; mt < 4; mt++)
#pragma unroll
        for (int nt = 0; nt < 4; nt++)
          acc[mt][nt] = mfma16(bF[nt], aF[mt], acc[mt][nt]);
    }
  }

  if (sec != 2) {
    const float qs = 0.180336880111120426f;  // 0.125 * log2(e) folded into Q
#pragma unroll
    for (int mt = 0; mt < 4; mt++) {
#pragma unroll
      for (int nt = 0; nt < 4; nt++) {
#pragma unroll
        for (int r = 0; r < 4; r++) {
          float v = acc[mt][nt][r];
          int m = m0 + wr * 64 + mt * 16 + quad * 4 + r;
          int n = n0 + wc * 64 + nt * 16 + l16;
          int ns = n & 1023;
          int h = ns >> 6, e = ns & 63;
          int b = m >> 11, t = m & 2047;
          size_t bh = (size_t)b * 16 + h;
          if (sec == 0) Qb[(bh * 2048 + t) * 64 + e] = f2b(v * qs);
          else          Kb[(bh * 2048 + t) * 64 + e] = f2b(v);
        }
      }
    }
  } else {
#pragma unroll
    for (int mt = 0; mt < 4; mt++) {
#pragma unroll
      for (int nt = 0; nt < 4; nt++) {
#pragma unroll
        for (int r = 0; r < 4; r++) {
          float v = acc[mt][nt][r];
          int n = n0 + wc * 64 + nt * 16 + quad * 4 + r;  // feature (row of C)
          int m = m0 + wr * 64 + mt * 16 + l16;           // token (col of C)
          int ns = n & 1023;
          int h = ns >> 6, e = ns & 63;
          int b = m >> 11, t = m & 2047;
          size_t bh = (size_t)b * 16 + h;
          Vt[(bh * 64 + e) * 2048 + t] = f2b(v);          // lanes -> consecutive t
        }
      }
    }
  }
}

// ---- flash attention v3: transposed S (A=K, B=Q); per-lane softmax state;
// paired Q-tiles (qb, 15-qb) per block -> uniform 17 j-iters/block.
// grid (bh=64, pair=8), block 512 (8 waves).
__global__ __launch_bounds__(512, 4) void attn(
    const u16* __restrict__ Q, const u16* __restrict__ K,
    const u16* __restrict__ Vt, u16* __restrict__ O) {
  __shared__ u16 lK[128 * 72];     // [s][e] pad+8
  __shared__ u16 lV[64 * 136];     // [e][s] pad+8
  __shared__ u16 lP[8 * 16 * 48];  // per-wave [16t][32s pad to 48]
  const int tid = threadIdx.x;
  const int lane = tid & 63, wave = tid >> 6;
  const int quad = lane >> 4, l16 = lane & 15;
  const int bh = blockIdx.x;
  const int pidx = blockIdx.y;     // 0..7
  const size_t base = (size_t)bh * (2048 * 64);
  u16* lPw = lP + wave * 768;
  const int b = bh >> 4, h = bh & 15;

  for (int half = 0; half < 2; half++) {
    const int qb = half ? pidx : (15 - pidx);   // long tile first
    const int t0 = qb << 7;
    const int tq = t0 + wave * 16 + l16;
    const bf16x8 qF0 = ldfrag(Q + base + (size_t)tq * 64 + quad * 8);
    const bf16x8 qF1 = ldfrag(Q + base + (size_t)tq * 64 + 32 + quad * 8);
    float m_i = -INFINITY, l_i = 0.f;
    f32x4 o[4] = {};

    for (int j = 0; j <= qb; j++) {
      const int s0 = j << 7;
      __syncthreads();
#pragma unroll
      for (int i = 0; i < 2; i++) {  // stage K tile 128x64
        int c = tid + i * 512;
        int r = c >> 3, col = (c & 7) * 8;
        *(us8*)&lK[r * 72 + col] = *(const us8*)(K + base + (size_t)(s0 + r) * 64 + col);
      }
#pragma unroll
      for (int i = 0; i < 2; i++) {  // stage Vt tile 64x128
        int c = tid + i * 512;
        int e = c >> 4, col = (c & 15) * 8;
        *(us8*)&lV[e * 136 + col] = *(const us8*)(Vt + base + (size_t)e * 2048 + s0 + col);
      }
      __syncthreads();

      // S^T = K·Q^T : lane owns col t=tq, rows s = nt*16+quad*4+r  (pre-scaled domain)
      f32x4 S[8];
#pragma unroll
      for (int nt = 0; nt < 8; nt++) {
        int sr = nt * 16 + l16;
        f32x4 a = {};
        a = mfma16(ldfrag(&lK[sr * 72 + quad * 8]), qF0, a);
        a = mfma16(ldfrag(&lK[sr * 72 + 32 + quad * 8]), qF1, a);
        S[nt] = a;
      }

      if (j == qb) {  // causal mask on diagonal tile
#pragma unroll
        for (int nt = 0; nt < 8; nt++)
#pragma unroll
          for (int r = 0; r < 4; r++) {
            int s = s0 + nt * 16 + quad * 4 + r;
            if (s > tq) S[nt][r] = -INFINITY;
          }
      }

      // online softmax: in-lane reduce + 2 cross-half shuffles; exp2 direct
      f32x4 m4 = S[0];
#pragma unroll
      for (int nt = 1; nt < 8; nt++)
#pragma unroll
        for (int r = 0; r < 4; r++) m4[r] = fmaxf(m4[r], S[nt][r]);
      float mx = fmaxf(fmaxf(m4[0], m4[1]), fmaxf(m4[2], m4[3]));
      mx = fmaxf(mx, __shfl_xor(mx, 16));
      mx = fmaxf(mx, __shfl_xor(mx, 32));
      float mn = fmaxf(m_i, mx);
      float alpha = __builtin_amdgcn_exp2f(m_i - mn);
      float sum = 0.f;
#pragma unroll
      for (int nt = 0; nt < 8; nt++)
#pragma unroll
        for (int r = 0; r < 4; r++) {
          float p = __builtin_amdgcn_exp2f(S[nt][r] - mn);
          S[nt][r] = p;
          sum += p;
        }
      sum += __shfl_xor(sum, 16);
      sum += __shfl_xor(sum, 32);
      l_i = l_i * alpha + sum;
      m_i = mn;
#pragma unroll
      for (int ot = 0; ot < 4; ot++)
#pragma unroll
        for (int r = 0; r < 4; r++) o[ot][r] *= alpha;

      // PV per 32-wide s-chunk: P^T through wave-private LDS (in-order DS, no barrier)
#pragma unroll
      for (int c = 0; c < 4; c++) {
        u32x2 d0 = { pkbf(S[2*c][0],   S[2*c][1]),   pkbf(S[2*c][2],   S[2*c][3]) };
        u32x2 d1 = { pkbf(S[2*c+1][0], S[2*c+1][1]), pkbf(S[2*c+1][2], S[2*c+1][3]) };
        *(u32x2*)&lPw[l16 * 48 + quad * 4]      = d0;  // s_local = quad*4+r
        *(u32x2*)&lPw[l16 * 48 + 16 + quad * 4] = d1;  // s_local = 16+quad*4+r
        __asm__ volatile("s_waitcnt lgkmcnt(0)" ::: "memory");
        bf16x8 bP = ldfrag(&lPw[l16 * 48 + quad * 8]);  // B-frag: n=t=l16, k=quad*8+j
#pragma unroll
        for (int ot = 0; ot < 4; ot++)
          o[ot] = mfma16(ldfrag(&lV[(ot * 16 + l16) * 136 + c * 32 + quad * 8]), bP, o[ot]);
      }
    }

    // O^T in C-layout: row e = ot*16+quad*4+r, col t = l16 -> per-lane 8B stores
    const float inv = 1.f / l_i;
#pragma unroll
    for (int ot = 0; ot < 4; ot++) {
      u32x2 pk = { pkbf(o[ot][0] * inv, o[ot][1] * inv),
                   pkbf(o[ot][2] * inv, o[ot][3] * inv) };
      *(u32x2*)&O[((size_t)b * 2048 + tq) * 1024 + h * 64 + ot * 16 + quad * 4] = pk;
    }
  }
}

// ---- GEMM2: out = Ao @ Wo^T + bo, fp32 epilogue. grid (8, 64), block 256.
__global__ __launch_bounds__(256) void gemm_out(
    const u16* __restrict__ A, const u16* __restrict__ W,
    const float* __restrict__ bias, float* __restrict__ out) {
  __shared__ u16 lA[128 * 32];
  __shared__ u16 lB[128 * 32];
  const int tid = threadIdx.x;
  const int lane = tid & 63, wave = tid >> 6;
  const int quad = lane >> 4, l16 = lane & 15;
  const int wr = wave >> 1, wc = wave & 1;
  const int m0 = blockIdx.y * 128;
  const int n0 = blockIdx.x * 128;
  AS3 u16* lA3 = (AS3 u16*)lA;
  AS3 u16* lB3 = (AS3 u16*)lB;
  f32x4 acc[4][4] = {};
  const int swg = (((tid & 3) ^ ((tid >> 3) & 3)) * 8);
  const int qsw = (quad ^ ((l16 >> 1) & 3)) * 8;
  const int c0 = tid, c1 = tid + 256;
  const int ar0 = m0 + (c0 >> 2);
  const int ar1 = m0 + (c1 >> 2);
  const int br0 = n0 + (c0 >> 2);
  const int br1 = n0 + (c1 >> 2);

  for (int k0 = 0; k0 < 1024; k0 += 32) {
    __syncthreads();
    gl_lds16(A + (size_t)ar0 * 1024 + k0 + swg, lA3 + wave * 512);
    gl_lds16(A + (size_t)ar1 * 1024 + k0 + swg, lA3 + 2048 + wave * 512);
    gl_lds16(W + (size_t)br0 * 1024 + k0 + swg, lB3 + wave * 512);
    gl_lds16(W + (size_t)br1 * 1024 + k0 + swg, lB3 + 2048 + wave * 512);
    __syncthreads();
    bf16x8 aF[4], bF[4];
#pragma unroll
    for (int mt = 0; mt < 4; mt++)
      aF[mt] = ldfrag(&lA[(wr * 64 + mt * 16 + l16) * 32 + qsw]);
#pragma unroll
    for (int nt = 0; nt < 4; nt++)
      bF[nt] = ldfrag(&lB[(wc * 64 + nt * 16 + l16) * 32 + qsw]);
#pragma unroll
    for (int mt = 0; mt < 4; mt++)
#pragma unroll
      for (int nt = 0; nt < 4; nt++)
        acc[mt][nt] = mfma16(aF[mt], bF[nt], acc[mt][nt]);
  }

#pragma unroll
  for (int mt = 0; mt < 4; mt++) {
#pragma unroll
    for (int nt = 0; nt < 4; nt++) {
#pragma unroll
      for (int r = 0; r < 4; r++) {
        int m = m0 + wr * 64 + mt * 16 + quad * 4 + r;
        int n = n0 + wc * 64 + nt * 16 + l16;
        out[(size_t)m * 1024 + n] = acc[mt][nt][r] + bias[n];
      }
    }
  }
}

extern "C" void kernel_launch(void* const* d_in, const int* in_sizes, int n_in,
                              void* d_out, int out_size, void* d_ws, size_t ws_size,
                              hipStream_t stream) {
  const float* x  = (const float*)d_in[0];
  const float* Wq = (const float*)d_in[1];
  const float* Wk = (const float*)d_in[2];
  const float* Wv = (const float*)d_in[3];
  const float* Wo = (const float*)d_in[4];
  const float* bo = (const float*)d_in[5];
  float* out = (float*)d_out;

  // ws (u16 elems), 40 MB total: xb/Ao | Wqkv | Wob | Qb.
  // d_out doubles as scratch for Kb+Vt (dead before gemm_out's fp32 write).
  u16* ws   = (u16*)d_ws;
  u16* xb   = ws;
  u16* Wqkv = ws + 8388608;
  u16* Wob  = ws + 11534336;
  u16* Qb   = ws + 12582912;
  u16* Ao   = xb;                       // lifetime-disjoint reuse
  u16* Kb   = (u16*)d_out;
  u16* Vt   = Kb + 8388608;

  cvt_bf16<<<8192, 256, 0, stream>>>(x, xb, 2097152);
  cvt_w<<<dim3(1024, 4), 256, 0, stream>>>(Wq, Wk, Wv, Wo, Wqkv, Wob);

  gemm_qkv<<<dim3(24, 32), 512, 0, stream>>>(xb, Wqkv, Qb, Kb, Vt);
  attn<<<dim3(64, 8), 512, 0, stream>>>(Qb, Kb, Vt, Ao);
  gemm_out<<<dim3(8, 64), 256, 0, stream>>>(Ao, Wob, bo, out);
}

// Round 8
// 269.388 us; speedup vs baseline: 2.8266x; 1.0763x over previous
//
#include <hip/hip_runtime.h>
#include <cstdint>
#include <cstddef>

// ---- types ----
typedef unsigned short u16;
typedef float  f32x4  __attribute__((ext_vector_type(4)));
typedef __bf16 bf16x8 __attribute__((ext_vector_type(8)));
typedef unsigned short us8 __attribute__((ext_vector_type(8)));
typedef unsigned short us4 __attribute__((ext_vector_type(4)));
typedef float  f32x4v __attribute__((ext_vector_type(4)));
typedef unsigned int u32x2 __attribute__((ext_vector_type(2)));

#define AS1 __attribute__((address_space(1)))
#define AS3 __attribute__((address_space(3)))

// fp32 -> bf16 round-to-nearest-even (scalar)
__device__ __forceinline__ u16 f2b(float f) {
  unsigned u = __float_as_uint(f);
  u += 0x7FFFu + ((u >> 16) & 1u);
  return (u16)(u >> 16);
}

// pack two fp32 -> bf16x2 dword (round-half-up; a = low 16, b = high 16)
__device__ __forceinline__ unsigned pkbf(float a, float b) {
  unsigned ua = __float_as_uint(a) + 0x8000u;
  unsigned ub = __float_as_uint(b) + 0x8000u;
  return __builtin_amdgcn_perm(ub, ua, 0x07060302u);
}

__device__ __forceinline__ bf16x8 ldfrag(const u16* p) {
  us8 v = *(const us8*)p;
  return __builtin_bit_cast(bf16x8, v);
}

__device__ __forceinline__ f32x4 mfma16(bf16x8 a, bf16x8 b, f32x4 c) {
  return __builtin_amdgcn_mfma_f32_16x16x32_bf16(a, b, c, 0, 0, 0);
}

// async global->LDS, 16B per lane; lds base must be wave-uniform (lane*16 auto-added)
__device__ __forceinline__ void gl_lds16(const u16* g, AS3 u16* l) {
  __builtin_amdgcn_global_load_lds((AS1 void*)g, (AS3 void*)l, 16, 0, 0);
}

// XOR-swizzled LDS tile layout (rows of 32 u16 = four 16B granules, 16-row chunks):
//   position(row r, granule g) = r*4 + (g ^ ((r>>1)&3))
// Staging lane L sources granule (L&3)^((L>>3)&3) so position == L (wave-uniform
// base + lane*16 stays legal for global_load_lds). Readers: quad ^ ((l16>>1)&3).
// R6: conflicts 6.29e6 -> 0.

// ---- fused cast: x + all 4 weights, one launch. grid 12288 x 256 ----
__global__ __launch_bounds__(256) void cvt_all(
    const float* __restrict__ x,
    const float* __restrict__ Wq, const float* __restrict__ Wk,
    const float* __restrict__ Wv, const float* __restrict__ Wo,
    u16* __restrict__ xb, u16* __restrict__ Wqkv, u16* __restrict__ Wob) {
  int blk = blockIdx.x;
  const float* s;
  u16* d;
  int i;
  if (blk < 8192)       { s = x;  d = xb;             i = blk * 256 + threadIdx.x; }
  else if (blk < 9216)  { s = Wq; d = Wqkv;           i = (blk - 8192) * 256 + threadIdx.x; }
  else if (blk < 10240) { s = Wk; d = Wqkv + 1048576; i = (blk - 9216) * 256 + threadIdx.x; }
  else if (blk < 11264) { s = Wv; d = Wqkv + 2097152; i = (blk - 10240) * 256 + threadIdx.x; }
  else                  { s = Wo; d = Wob;            i = (blk - 11264) * 256 + threadIdx.x; }
  f32x4v f = ((const f32x4v*)s)[i];
  us4 o = { f2b(f[0]), f2b(f[1]), f2b(f[2]), f2b(f[3]) };
  ((us4*)d)[i] = o;
}

// ---- GEMM1: C = X @ Wqkv^T -> Q (prescaled by 0.125*log2e), K, Vt.
// m97 configuration (874 TF measured on this HW): 128x128 tile, 256 threads,
// BK=32, single-buffered 2-barrier K-loop, ~160 VGPR -> 3 blocks/CU (12
// independent waves/CU de-correlate barrier stalls — m114). R7 showed the
// 512-thread/1-block-per-CU variant caps at 525 TF with dbuf neutral.
// grid (24, 64).
__global__ __launch_bounds__(256) void gemm_qkv(
    const u16* __restrict__ A, const u16* __restrict__ W,
    u16* __restrict__ Qb, u16* __restrict__ Kb, u16* __restrict__ Vt) {
  __shared__ u16 lA[128 * 32];   // 8 KB
  __shared__ u16 lB[128 * 32];   // 8 KB
  const int tid = threadIdx.x;
  const int lane = tid & 63, wave = tid >> 6;
  const int quad = lane >> 4, l16 = lane & 15;
  const int wr = wave >> 1, wc = wave & 1;
  const int m0 = blockIdx.y * 128;
  const int n0 = blockIdx.x * 128;
  const int sec = n0 >> 10;  // 0=Q 1=K 2=V
  AS3 u16* lA3 = (AS3 u16*)lA;
  AS3 u16* lB3 = (AS3 u16*)lB;
  f32x4 acc[4][4] = {};
  const int swg = (((tid & 3) ^ ((tid >> 3) & 3)) * 8);  // staging source granule
  const int qsw = (quad ^ ((l16 >> 1) & 3)) * 8;         // reader granule
  const int ar0 = m0 + (tid >> 2);          // rows 0..63 (+64 for second inst)
  const int br0 = n0 + (tid >> 2);

  const u16* gA0 = A + (size_t)ar0 * 1024 + swg;
  const u16* gA1 = gA0 + 64 * 1024;
  const u16* gB0 = W + (size_t)br0 * 1024 + swg;
  const u16* gB1 = gB0 + 64 * 1024;

  for (int k0 = 0; k0 < 1024; k0 += 32) {
    __syncthreads();
    gl_lds16(gA0 + k0, lA3 + wave * 512);
    gl_lds16(gA1 + k0, lA3 + 2048 + wave * 512);
    gl_lds16(gB0 + k0, lB3 + wave * 512);
    gl_lds16(gB1 + k0, lB3 + 2048 + wave * 512);
    __syncthreads();
    bf16x8 aF[4], bF[4];
#pragma unroll
    for (int mt = 0; mt < 4; mt++)
      aF[mt] = ldfrag(&lA[(wr * 64 + mt * 16 + l16) * 32 + qsw]);
#pragma unroll
    for (int nt = 0; nt < 4; nt++)
      bF[nt] = ldfrag(&lB[(wc * 64 + nt * 16 + l16) * 32 + qsw]);
    if (sec != 2) {
#pragma unroll
      for (int mt = 0; mt < 4; mt++)
#pragma unroll
        for (int nt = 0; nt < 4; nt++)
          acc[mt][nt] = mfma16(aF[mt], bF[nt], acc[mt][nt]);
    } else {  // transposed accumulate: C[n][m]
#pragma unroll
      for (int mt = 0; mt < 4; mt++)
#pragma unroll
        for (int nt = 0; nt < 4; nt++)
          acc[mt][nt] = mfma16(bF[nt], aF[mt], acc[mt][nt]);
    }
  }

  if (sec != 2) {
    const float qs = 0.180336880111120426f;  // 0.125 * log2(e) folded into Q
#pragma unroll
    for (int mt = 0; mt < 4; mt++) {
#pragma unroll
      for (int nt = 0; nt < 4; nt++) {
#pragma unroll
        for (int r = 0; r < 4; r++) {
          float v = acc[mt][nt][r];
          int m = m0 + wr * 64 + mt * 16 + quad * 4 + r;
          int n = n0 + wc * 64 + nt * 16 + l16;
          int ns = n & 1023;
          int h = ns >> 6, e = ns & 63;
          int b = m >> 11, t = m & 2047;
          size_t bh = (size_t)b * 16 + h;
          if (sec == 0) Qb[(bh * 2048 + t) * 64 + e] = f2b(v * qs);
          else          Kb[(bh * 2048 + t) * 64 + e] = f2b(v);
        }
      }
    }
  } else {
#pragma unroll
    for (int mt = 0; mt < 4; mt++) {
#pragma unroll
      for (int nt = 0; nt < 4; nt++) {
#pragma unroll
        for (int r = 0; r < 4; r++) {
          float v = acc[mt][nt][r];
          int n = n0 + wc * 64 + nt * 16 + quad * 4 + r;  // feature (row of C)
          int m = m0 + wr * 64 + mt * 16 + l16;           // token (col of C)
          int ns = n & 1023;
          int h = ns >> 6, e = ns & 63;
          int b = m >> 11, t = m & 2047;
          size_t bh = (size_t)b * 16 + h;
          Vt[(bh * 64 + e) * 2048 + t] = f2b(v);          // lanes -> consecutive t
        }
      }
    }
  }
}

// ---- flash attention v3: transposed S (A=K, B=Q); per-lane softmax state;
// paired Q-tiles (qb, 15-qb) per block -> uniform 17 j-iters/block.
// grid (bh=64, pair=8), block 512 (8 waves).
__global__ __launch_bounds__(512, 4) void attn(
    const u16* __restrict__ Q, const u16* __restrict__ K,
    const u16* __restrict__ Vt, u16* __restrict__ O) {
  __shared__ u16 lK[128 * 72];     // [s][e] pad+8
  __shared__ u16 lV[64 * 136];     // [e][s] pad+8
  __shared__ u16 lP[8 * 16 * 48];  // per-wave [16t][32s pad to 48]
  const int tid = threadIdx.x;
  const int lane = tid & 63, wave = tid >> 6;
  const int quad = lane >> 4, l16 = lane & 15;
  const int bh = blockIdx.x;
  const int pidx = blockIdx.y;     // 0..7
  const size_t base = (size_t)bh * (2048 * 64);
  u16* lPw = lP + wave * 768;
  const int b = bh >> 4, h = bh & 15;

  for (int half = 0; half < 2; half++) {
    const int qb = half ? pidx : (15 - pidx);   // long tile first
    const int t0 = qb << 7;
    const int tq = t0 + wave * 16 + l16;
    const bf16x8 qF0 = ldfrag(Q + base + (size_t)tq * 64 + quad * 8);
    const bf16x8 qF1 = ldfrag(Q + base + (size_t)tq * 64 + 32 + quad * 8);
    float m_i = -INFINITY, l_i = 0.f;
    f32x4 o[4] = {};

    for (int j = 0; j <= qb; j++) {
      const int s0 = j << 7;
      __syncthreads();
#pragma unroll
      for (int i = 0; i < 2; i++) {  // stage K tile 128x64
        int c = tid + i * 512;
        int r = c >> 3, col = (c & 7) * 8;
        *(us8*)&lK[r * 72 + col] = *(const us8*)(K + base + (size_t)(s0 + r) * 64 + col);
      }
#pragma unroll
      for (int i = 0; i < 2; i++) {  // stage Vt tile 64x128
        int c = tid + i * 512;
        int e = c >> 4, col = (c & 15) * 8;
        *(us8*)&lV[e * 136 + col] = *(const us8*)(Vt + base + (size_t)e * 2048 + s0 + col);
      }
      __syncthreads();

      // S^T = K·Q^T : lane owns col t=tq, rows s = nt*16+quad*4+r  (pre-scaled domain)
      f32x4 S[8];
#pragma unroll
      for (int nt = 0; nt < 8; nt++) {
        int sr = nt * 16 + l16;
        f32x4 a = {};
        a = mfma16(ldfrag(&lK[sr * 72 + quad * 8]), qF0, a);
        a = mfma16(ldfrag(&lK[sr * 72 + 32 + quad * 8]), qF1, a);
        S[nt] = a;
      }

      if (j == qb) {  // causal mask on diagonal tile
#pragma unroll
        for (int nt = 0; nt < 8; nt++)
#pragma unroll
          for (int r = 0; r < 4; r++) {
            int s = s0 + nt * 16 + quad * 4 + r;
            if (s > tq) S[nt][r] = -INFINITY;
          }
      }

      // online softmax: in-lane reduce + 2 cross-half shuffles; exp2 direct
      f32x4 m4 = S[0];
#pragma unroll
      for (int nt = 1; nt < 8; nt++)
#pragma unroll
        for (int r = 0; r < 4; r++) m4[r] = fmaxf(m4[r], S[nt][r]);
      float mx = fmaxf(fmaxf(m4[0], m4[1]), fmaxf(m4[2], m4[3]));
      mx = fmaxf(mx, __shfl_xor(mx, 16));
      mx = fmaxf(mx, __shfl_xor(mx, 32));
      float mn = fmaxf(m_i, mx);
      float alpha = __builtin_amdgcn_exp2f(m_i - mn);
      float sum = 0.f;
#pragma unroll
      for (int nt = 0; nt < 8; nt++)
#pragma unroll
        for (int r = 0; r < 4; r++) {
          float p = __builtin_amdgcn_exp2f(S[nt][r] - mn);
          S[nt][r] = p;
          sum += p;
        }
      sum += __shfl_xor(sum, 16);
      sum += __shfl_xor(sum, 32);
      l_i = l_i * alpha + sum;
      m_i = mn;
#pragma unroll
      for (int ot = 0; ot < 4; ot++)
#pragma unroll
        for (int r = 0; r < 4; r++) o[ot][r] *= alpha;

      // PV per 32-wide s-chunk: P^T through wave-private LDS (in-order DS, no barrier)
#pragma unroll
      for (int c = 0; c < 4; c++) {
        u32x2 d0 = { pkbf(S[2*c][0],   S[2*c][1]),   pkbf(S[2*c][2],   S[2*c][3]) };
        u32x2 d1 = { pkbf(S[2*c+1][0], S[2*c+1][1]), pkbf(S[2*c+1][2], S[2*c+1][3]) };
        *(u32x2*)&lPw[l16 * 48 + quad * 4]      = d0;  // s_local = quad*4+r
        *(u32x2*)&lPw[l16 * 48 + 16 + quad * 4] = d1;  // s_local = 16+quad*4+r
        __asm__ volatile("s_waitcnt lgkmcnt(0)" ::: "memory");
        bf16x8 bP = ldfrag(&lPw[l16 * 48 + quad * 8]);  // B-frag: n=t=l16, k=quad*8+j
#pragma unroll
        for (int ot = 0; ot < 4; ot++)
          o[ot] = mfma16(ldfrag(&lV[(ot * 16 + l16) * 136 + c * 32 + quad * 8]), bP, o[ot]);
      }
    }

    // O^T in C-layout: row e = ot*16+quad*4+r, col t = l16 -> per-lane 8B stores
    const float inv = 1.f / l_i;
#pragma unroll
    for (int ot = 0; ot < 4; ot++) {
      u32x2 pk = { pkbf(o[ot][0] * inv, o[ot][1] * inv),
                   pkbf(o[ot][2] * inv, o[ot][3] * inv) };
      *(u32x2*)&O[((size_t)b * 2048 + tq) * 1024 + h * 64 + ot * 16 + quad * 4] = pk;
    }
  }
}

// ---- GEMM2: out = Ao @ Wo^T + bo, fp32 epilogue. grid (8, 64), block 256.
__global__ __launch_bounds__(256) void gemm_out(
    const u16* __restrict__ A, const u16* __restrict__ W,
    const float* __restrict__ bias, float* __restrict__ out) {
  __shared__ u16 lA[128 * 32];
  __shared__ u16 lB[128 * 32];
  const int tid = threadIdx.x;
  const int lane = tid & 63, wave = tid >> 6;
  const int quad = lane >> 4, l16 = lane & 15;
  const int wr = wave >> 1, wc = wave & 1;
  const int m0 = blockIdx.y * 128;
  const int n0 = blockIdx.x * 128;
  AS3 u16* lA3 = (AS3 u16*)lA;
  AS3 u16* lB3 = (AS3 u16*)lB;
  f32x4 acc[4][4] = {};
  const int swg = (((tid & 3) ^ ((tid >> 3) & 3)) * 8);
  const int qsw = (quad ^ ((l16 >> 1) & 3)) * 8;
  const int ar0 = m0 + (tid >> 2);
  const int br0 = n0 + (tid >> 2);
  const u16* gA0 = A + (size_t)ar0 * 1024 + swg;
  const u16* gA1 = gA0 + 64 * 1024;
  const u16* gB0 = W + (size_t)br0 * 1024 + swg;
  const u16* gB1 = gB0 + 64 * 1024;

  for (int k0 = 0; k0 < 1024; k0 += 32) {
    __syncthreads();
    gl_lds16(gA0 + k0, lA3 + wave * 512);
    gl_lds16(gA1 + k0, lA3 + 2048 + wave * 512);
    gl_lds16(gB0 + k0, lB3 + wave * 512);
    gl_lds16(gB1 + k0, lB3 + 2048 + wave * 512);
    __syncthreads();
    bf16x8 aF[4], bF[4];
#pragma unroll
    for (int mt = 0; mt < 4; mt++)
      aF[mt] = ldfrag(&lA[(wr * 64 + mt * 16 + l16) * 32 + qsw]);
#pragma unroll
    for (int nt = 0; nt < 4; nt++)
      bF[nt] = ldfrag(&lB[(wc * 64 + nt * 16 + l16) * 32 + qsw]);
#pragma unroll
    for (int mt = 0; mt < 4; mt++)
#pragma unroll
      for (int nt = 0; nt < 4; nt++)
        acc[mt][nt] = mfma16(aF[mt], bF[nt], acc[mt][nt]);
  }

#pragma unroll
  for (int mt = 0; mt < 4; mt++) {
#pragma unroll
    for (int nt = 0; nt < 4; nt++) {
#pragma unroll
      for (int r = 0; r < 4; r++) {
        int m = m0 + wr * 64 + mt * 16 + quad * 4 + r;
        int n = n0 + wc * 64 + nt * 16 + l16;
        out[(size_t)m * 1024 + n] = acc[mt][nt][r] + bias[n];
      }
    }
  }
}

extern "C" void kernel_launch(void* const* d_in, const int* in_sizes, int n_in,
                              void* d_out, int out_size, void* d_ws, size_t ws_size,
                              hipStream_t stream) {
  const float* x  = (const float*)d_in[0];
  const float* Wq = (const float*)d_in[1];
  const float* Wk = (const float*)d_in[2];
  const float* Wv = (const float*)d_in[3];
  const float* Wo = (const float*)d_in[4];
  const float* bo = (const float*)d_in[5];
  float* out = (float*)d_out;

  // ws (u16 elems), 40 MB total: xb/Ao | Wqkv | Wob | Qb.
  // d_out doubles as scratch for Kb+Vt (dead before gemm_out's fp32 write).
  u16* ws   = (u16*)d_ws;
  u16* xb   = ws;
  u16* Wqkv = ws + 8388608;
  u16* Wob  = ws + 11534336;
  u16* Qb   = ws + 12582912;
  u16* Ao   = xb;                       // lifetime-disjoint reuse
  u16* Kb   = (u16*)d_out;
  u16* Vt   = Kb + 8388608;

  cvt_all<<<12288, 256, 0, stream>>>(x, Wq, Wk, Wv, Wo, xb, Wqkv, Wob);
  gemm_qkv<<<dim3(24, 64), 256, 0, stream>>>(xb, Wqkv, Qb, Kb, Vt);
  attn<<<dim3(64, 8), 512, 0, stream>>>(Qb, Kb, Vt, Ao);
  gemm_out<<<dim3(8, 64), 256, 0, stream>>>(Ao, Wob, bo, out);
}